// Round 2
// baseline (173.231 us; speedup 1.0000x reference)
//
#include <hip/hip_runtime.h>
#include <hip/hip_cooperative_groups.h>
#include <cmath>

namespace cg = cooperative_groups;

#define MATSZ 262144              // 2048 rows * 128
// ws layout (floats):
//   wt  [128][512]  @ 0        (65536)   Wt[k][m*128+c], m: 0=q 1=k 2=v 3=o
//   qkv [3][64][512][8] @ 65536 (786432)
//   aout[2048][128] @ 851968   (262144)
#define WT_OFF   0
#define QKV_OFF  65536
#define AOUT_OFF (65536 + 3 * MATSZ)

// -------- Kernel A: transpose the four 128x128 weight matrices ---------------
__global__ __launch_bounds__(256) void k_transpose(
    const float* __restrict__ Wq, const float* __restrict__ Wk,
    const float* __restrict__ Wv, const float* __restrict__ Wo,
    float* __restrict__ ws) {
  int idx = blockIdx.x * 256 + threadIdx.x;
  if (idx < 65536) {
    int m = idx >> 14;
    int c = (idx >> 7) & 127;
    int k = idx & 127;
    const float* W = (m == 0) ? Wq : (m == 1) ? Wk : (m == 2) ? Wv : Wo;
    ws[WT_OFF + k * 512 + m * 128 + c] = W[c * 128 + k];  // read coalesced in k
  }
}

// -------- Kernel B: cooperative fused pipeline -------------------------------
// phase 0: QKV proj + quantum closed form -> qkv[m][bh][s][8]
// phase 1: attention per (bh, 64-row q-tile) -> aout[row][128]
// phase 2: out = aout @ Wo^T
__global__ __launch_bounds__(256, 4) void k_main(
    const float* __restrict__ x, const float* __restrict__ qp,
    float* __restrict__ ws, float* __restrict__ out,
    int coop, int plo, int phi) {
  __shared__ float smem[8192];  // 32 KB
  cg::grid_group grid = cg::this_grid();
  const int t = threadIdx.x;
  const int bid = blockIdx.x;
  const int G = gridDim.x;
  float* qkv = ws + QKV_OFF;
  float* aout = ws + AOUT_OFF;

  // ---------------- Phase 0: QKV + quantum ----------------
  if (plo <= 0) {
    float qsum[8];
#pragma unroll
    for (int j = 0; j < 8; ++j) qsum[j] = qp[j] + qp[8 + j];
    for (int vbb = bid; vbb < 1024; vbb += G) {
      int sel = vbb & 7;
      if (sel < 3) {                       // 384 active vbs, spread over bids
        int vb = (vbb >> 3) * 3 + sel;     // [0,384)
        int tile = vb / 3;                 // 16 rows
        int m = vb - tile * 3;
        __syncthreads();
        {  // stage x tile (16x128)
          const float4* xgv = (const float4*)(x + (size_t)tile * 2048);
          float4* xs = (float4*)smem;
          xs[t] = xgv[t];
          xs[t + 256] = xgv[t + 256];
        }
        __syncthreads();
        const int c = t & 127, rg = t >> 7;
        const float* wcol = ws + WT_OFF + m * 128 + c;  // stride 512 per k
        float acc[8] = {0.f, 0.f, 0.f, 0.f, 0.f, 0.f, 0.f, 0.f};
        const float4* xs4 = (const float4*)smem + rg * 8 * 32;
#pragma unroll 4
        for (int kc = 0; kc < 32; ++kc) {
          float w0 = wcol[(kc * 4 + 0) * 512];
          float w1 = wcol[(kc * 4 + 1) * 512];
          float w2 = wcol[(kc * 4 + 2) * 512];
          float w3 = wcol[(kc * 4 + 3) * 512];
#pragma unroll
          for (int r = 0; r < 8; ++r) {
            float4 xv = xs4[r * 32 + kc];  // LDS broadcast
            acc[r] = fmaf(xv.x, w0, acc[r]);
            acc[r] = fmaf(xv.y, w1, acc[r]);
            acc[r] = fmaf(xv.z, w2, acc[r]);
            acc[r] = fmaf(xv.w, w3, acc[r]);
          }
        }
        float* th = smem + 2048;
#pragma unroll
        for (int r = 0; r < 8; ++r) th[(rg * 8 + r) * 128 + c] = acc[r];
        __syncthreads();
        {  // quantum closed form: thread -> (row r, head h)
          int r = t >> 4, h = t & 15;
          const float* tb = th + r * 128 + h * 8;
          float o[8];
          float pe = 1.f, po = 1.f;
#pragma unroll
          for (int j = 0; j < 8; ++j) {
            float cj = __cosf(tb[j] + qsum[j]);
            if (j & 1) { po *= cj; o[j] = po; }
            else       { pe *= cj; o[j] = pe; }
          }
          int row = tile * 16 + r;
          int b = row >> 9, s = row & 511;
          float* dst = qkv + (size_t)m * MATSZ +
                       ((size_t)((b << 4) + h) * 512 + s) * 8;
          ((float4*)dst)[0] = make_float4(o[0], o[1], o[2], o[3]);
          ((float4*)dst)[1] = make_float4(o[4], o[5], o[6], o[7]);
        }
        __syncthreads();
      }
    }
  }

  if (coop) grid.sync();

  // ---------------- Phase 1: attention ----------------
  if (plo <= 1 && phi >= 1) {
    const float scale = 0.35355339059327373f;  // 1/sqrt(8)
    for (int vbb = bid; vbb < 1024; vbb += G) {
      if (vbb & 1) continue;     // 512 active vbs -> 2 blocks/CU, spread
      int vb = vbb >> 1;         // [0,512)
      int bh = vb >> 3;
      int qt = vb & 7;           // 64-row q tile
      const float* Qg = qkv + (size_t)bh * 4096;
      const float* Kg = qkv + MATSZ + (size_t)bh * 4096;
      const float* Vg = qkv + 2 * (size_t)MATSZ + (size_t)bh * 4096;
      __syncthreads();
      {  // stage K,V (16 KB each)
        const float4* kgv = (const float4*)Kg;
        const float4* vgv = (const float4*)Vg;
        float4* ksv = (float4*)smem;
        float4* vsv = (float4*)smem + 1024;
#pragma unroll
        for (int i = 0; i < 4; ++i) {
          ksv[t + i * 256] = kgv[t + i * 256];
          vsv[t + i * 256] = vgv[t + i * 256];
        }
      }
      __syncthreads();
      const int qslot = t >> 3, ko = t & 7;
      const int row0 = qt * 64 + qslot * 2;  // local s of first q row
      float4 qa0 = ((const float4*)(Qg + (size_t)row0 * 8))[0];
      float4 qb0 = ((const float4*)(Qg + (size_t)row0 * 8))[1];
      float4 qa1 = ((const float4*)(Qg + (size_t)(row0 + 1) * 8))[0];
      float4 qb1 = ((const float4*)(Qg + (size_t)(row0 + 1) * 8))[1];
      qa0.x *= scale; qa0.y *= scale; qa0.z *= scale; qa0.w *= scale;
      qb0.x *= scale; qb0.y *= scale; qb0.z *= scale; qb0.w *= scale;
      qa1.x *= scale; qa1.y *= scale; qa1.z *= scale; qa1.w *= scale;
      qb1.x *= scale; qb1.y *= scale; qb1.z *= scale; qb1.w *= scale;
      float l0 = 0.f, l1 = 0.f;
      float a0[8] = {0.f, 0.f, 0.f, 0.f, 0.f, 0.f, 0.f, 0.f};
      float a1[8] = {0.f, 0.f, 0.f, 0.f, 0.f, 0.f, 0.f, 0.f};
      const float4* ksv = (const float4*)smem;
      const float4* vsv = (const float4*)smem + 1024;
#pragma unroll 4
      for (int i = 0; i < 64; ++i) {
        int k = i * 8 + ko;  // stride-8 interleave: 2-way LDS conflict = free
        float4 kx = ksv[k * 2], ky = ksv[k * 2 + 1];
        float4 vx = vsv[k * 2], vy = vsv[k * 2 + 1];
        float s0 = qa0.x * kx.x + qa0.y * kx.y + qa0.z * kx.z + qa0.w * kx.w +
                   qb0.x * ky.x + qb0.y * ky.y + qb0.z * ky.z + qb0.w * ky.w;
        float s1 = qa1.x * kx.x + qa1.y * kx.y + qa1.z * kx.z + qa1.w * kx.w +
                   qb1.x * ky.x + qb1.y * ky.y + qb1.z * ky.z + qb1.w * ky.w;
        float p0 = __expf(s0), p1 = __expf(s1);  // |s|<=2.83, no max needed
        l0 += p0; l1 += p1;
        a0[0] = fmaf(p0, vx.x, a0[0]); a1[0] = fmaf(p1, vx.x, a1[0]);
        a0[1] = fmaf(p0, vx.y, a0[1]); a1[1] = fmaf(p1, vx.y, a1[1]);
        a0[2] = fmaf(p0, vx.z, a0[2]); a1[2] = fmaf(p1, vx.z, a1[2]);
        a0[3] = fmaf(p0, vx.w, a0[3]); a1[3] = fmaf(p1, vx.w, a1[3]);
        a0[4] = fmaf(p0, vy.x, a0[4]); a1[4] = fmaf(p1, vy.x, a1[4]);
        a0[5] = fmaf(p0, vy.y, a0[5]); a1[5] = fmaf(p1, vy.y, a1[5]);
        a0[6] = fmaf(p0, vy.z, a0[6]); a1[6] = fmaf(p1, vy.z, a1[6]);
        a0[7] = fmaf(p0, vy.w, a0[7]); a1[7] = fmaf(p1, vy.w, a1[7]);
      }
#pragma unroll
      for (int mm = 1; mm <= 4; mm <<= 1) {  // reduce over 8 k-octants
        l0 += __shfl_xor(l0, mm);
        l1 += __shfl_xor(l1, mm);
#pragma unroll
        for (int j = 0; j < 8; ++j) {
          a0[j] += __shfl_xor(a0[j], mm);
          a1[j] += __shfl_xor(a1[j], mm);
        }
      }
      if (ko == 0) {
        float i0 = 1.f / l0, i1 = 1.f / l1;
        int b = bh >> 4, h = bh & 15;
        float* d0 = aout + ((size_t)(b * 512 + row0)) * 128 + h * 8;
        ((float4*)d0)[0] = make_float4(a0[0] * i0, a0[1] * i0, a0[2] * i0, a0[3] * i0);
        ((float4*)d0)[1] = make_float4(a0[4] * i0, a0[5] * i0, a0[6] * i0, a0[7] * i0);
        float* d1 = d0 + 128;
        ((float4*)d1)[0] = make_float4(a1[0] * i1, a1[1] * i1, a1[2] * i1, a1[3] * i1);
        ((float4*)d1)[1] = make_float4(a1[4] * i1, a1[5] * i1, a1[6] * i1, a1[7] * i1);
      }
      __syncthreads();
    }
  }

  if (coop) grid.sync();

  // ---------------- Phase 2: out = aout @ Wo^T ----------------
  if (phi >= 2) {
    for (int vbb = bid; vbb < 1024; vbb += G) {
      if (vbb & 3) continue;  // 256 active vbs, spread 1/CU
      int vb = vbb >> 2;      // rows vb*8 .. +7
      __syncthreads();
      {
        const float4* ag = (const float4*)(aout + (size_t)vb * 1024);
        ((float4*)smem)[t] = ag[t];
      }
      __syncthreads();
      const int c = t & 127, rg = t >> 7;
      const float* wcol = ws + WT_OFF + 384 + c;  // Wo^T column
      float acc[4] = {0.f, 0.f, 0.f, 0.f};
      const float4* as4 = (const float4*)smem + rg * 4 * 32;
#pragma unroll 4
      for (int kc = 0; kc < 32; ++kc) {
        float w0 = wcol[(kc * 4 + 0) * 512];
        float w1 = wcol[(kc * 4 + 1) * 512];
        float w2 = wcol[(kc * 4 + 2) * 512];
        float w3 = wcol[(kc * 4 + 3) * 512];
#pragma unroll
        for (int r = 0; r < 4; ++r) {
          float4 av = as4[r * 32 + kc];
          acc[r] = fmaf(av.x, w0, acc[r]);
          acc[r] = fmaf(av.y, w1, acc[r]);
          acc[r] = fmaf(av.z, w2, acc[r]);
          acc[r] = fmaf(av.w, w3, acc[r]);
        }
      }
#pragma unroll
      for (int r = 0; r < 4; ++r)
        out[(size_t)(vb * 8 + rg * 4 + r) * 128 + c] = acc[r];
      __syncthreads();
    }
  }
}

extern "C" void kernel_launch(void* const* d_in, const int* in_sizes, int n_in,
                              void* d_out, int out_size, void* d_ws, size_t ws_size,
                              hipStream_t stream) {
  const float* x  = (const float*)d_in[0];
  const float* Wq = (const float*)d_in[1];
  const float* Wk = (const float*)d_in[2];
  const float* Wv = (const float*)d_in[3];
  const float* Wo = (const float*)d_in[4];
  const float* qp = (const float*)d_in[5];
  float* out = (float*)d_out;
  float* ws = (float*)d_ws;

  hipLaunchKernelGGL(k_transpose, dim3(256), dim3(256), 0, stream,
                     Wq, Wk, Wv, Wo, ws);

  hipDeviceProp_t prop;
  hipGetDeviceProperties(&prop, 0);
  int maxBlk = 0;
  hipOccupancyMaxActiveBlocksPerMultiprocessor(&maxBlk, k_main, 256, 0);
  if (maxBlk < 1) maxBlk = 1;
  if (maxBlk > 4) maxBlk = 4;
  int grid = prop.multiProcessorCount * maxBlk;
  if (grid > 1024) grid = 1024;

  int coop = 1, plo = 0, phi = 2;
  void* args[] = {(void*)&x, (void*)&qp, (void*)&ws, (void*)&out,
                  (void*)&coop, (void*)&plo, (void*)&phi};
  hipError_t err = hipLaunchCooperativeKernel((const void*)k_main, dim3(grid),
                                              dim3(256), args, 0, stream);
  if (err != hipSuccess) {
    (void)hipGetLastError();  // clear; fall back to 3 plain launches
    hipLaunchKernelGGL(k_main, dim3(grid), dim3(256), 0, stream,
                       x, qp, ws, out, 0, 0, 0);
    hipLaunchKernelGGL(k_main, dim3(grid), dim3(256), 0, stream,
                       x, qp, ws, out, 0, 1, 1);
    hipLaunchKernelGGL(k_main, dim3(grid), dim3(256), 0, stream,
                       x, qp, ws, out, 0, 2, 2);
  }
}

// Round 3
// 49.326 us; speedup vs baseline: 3.5120x; 3.5120x over previous
//
#include <hip/hip_runtime.h>
#include <cmath>

#define MATSZ 262144              // 2048 * 128
#define WT_OFF 0                  // wt[4][128][128]: wt[m][k][c] = W_m[c][k]
#define QKV_OFF 65536             // qkv[3][64][512][8]
#define AOUT_OFF (65536 + 3 * MATSZ)  // aout[2048][128]

// ---------------- k_prep: transpose the 4 weight matrices --------------------
__global__ __launch_bounds__(256) void k_prep(
    const float* __restrict__ Wq, const float* __restrict__ Wk,
    const float* __restrict__ Wv, const float* __restrict__ Wo,
    float* __restrict__ ws) {
  __shared__ float s[32][33];
  const int m = blockIdx.y;
  const int tr = blockIdx.x >> 2;  // c-tile
  const int tc = blockIdx.x & 3;   // k-tile
  const float* W = (m == 0) ? Wq : (m == 1) ? Wk : (m == 2) ? Wv : Wo;
  const int lk = threadIdx.x & 31;
  const int l0 = threadIdx.x >> 5;
#pragma unroll
  for (int i = 0; i < 4; ++i) {
    int lc = l0 + i * 8;
    s[lc][lk] = W[(size_t)(tr * 32 + lc) * 128 + tc * 32 + lk];  // coalesced
  }
  __syncthreads();
  float* wt = ws + WT_OFF + m * 16384;
#pragma unroll
  for (int i = 0; i < 4; ++i) {
    int lkk = l0 + i * 8;
    wt[(size_t)(tc * 32 + lkk) * 128 + tr * 32 + lk] = s[lk][lkk];  // coalesced
  }
}

// ---------------- k_qkvq: QKV projection + quantum closed form ---------------
// grid (256,3): tile of 8 rows x matrix m. thread = 1 row x 4 cols, full K.
__global__ __launch_bounds__(256, 4) void k_qkvq(
    const float* __restrict__ x, const float* __restrict__ qp,
    float* __restrict__ ws) {
  __shared__ float xs[8][128];
  __shared__ float th[8][128];
  const int t = threadIdx.x;
  const int tile = blockIdx.x;  // 0..255
  const int m = blockIdx.y;     // 0..2
  {
    const float4* xg = (const float4*)(x + (size_t)tile * 1024);
    ((float4*)&xs[0][0])[t] = xg[t];
  }
  __syncthreads();
  const int cg = t & 31, rg = t >> 5;
  const float4* wt4 = (const float4*)(ws + WT_OFF + m * 16384);
  const float* xr = &xs[rg][0];
  float4 acc = make_float4(0.f, 0.f, 0.f, 0.f);
#pragma unroll 8
  for (int k = 0; k < 128; ++k) {
    float4 w = wt4[k * 32 + cg];  // lanes contiguous -> coalesced, L1/L2 hot
    float xv = xr[k];             // LDS broadcast
    acc.x = fmaf(xv, w.x, acc.x);
    acc.y = fmaf(xv, w.y, acc.y);
    acc.z = fmaf(xv, w.z, acc.z);
    acc.w = fmaf(xv, w.w, acc.w);
  }
  // quantum: c_j = cos(theta_j + qsum_j); cols 4cg..4cg+3, j = col mod 8
  const int j0 = (cg & 1) * 4;
  float4 cc;
  cc.x = __cosf(acc.x + qp[j0 + 0] + qp[8 + j0 + 0]);
  cc.y = __cosf(acc.y + qp[j0 + 1] + qp[8 + j0 + 1]);
  cc.z = __cosf(acc.z + qp[j0 + 2] + qp[8 + j0 + 2]);
  cc.w = __cosf(acc.w + qp[j0 + 3] + qp[8 + j0 + 3]);
  ((float4*)&th[rg][0])[cg] = cc;
  __syncthreads();
  if (t < 128) {  // parity-chain prefix products, 8 rows x 16 heads
    const int r = t >> 4, h = t & 15;
    const float* tb = &th[r][h * 8];
    float o0 = tb[0], o1 = tb[1];
    float o2 = o0 * tb[2], o3 = o1 * tb[3];
    float o4 = o2 * tb[4], o5 = o3 * tb[5];
    float o6 = o4 * tb[6], o7 = o5 * tb[7];
    int row = tile * 8 + r;
    int b = row >> 9, s = row & 511;
    float* dst = ws + QKV_OFF + (size_t)m * MATSZ +
                 ((size_t)((b << 4) + h) * 512 + s) * 8;
    ((float4*)dst)[0] = make_float4(o0, o1, o2, o3);
    ((float4*)dst)[1] = make_float4(o4, o5, o6, o7);
  }
}

// ---------------- k_attn: attention per (bh, 32-row q-tile) ------------------
// grid (16,64); block 256 = 16 qslots (2 rows each) x 16 k-octants.
// K/V stored as lo/hi float4 arrays (16B rows) -> interleaved k access is
// 2-way bank aliasing (free).
__global__ __launch_bounds__(256, 4) void k_attn(
    float* __restrict__ ws) {
  __shared__ float4 kslo[512], kshi[512], vslo[512], vshi[512];
  const int qt = blockIdx.x;  // 0..15
  const int bh = blockIdx.y;  // 0..63
  const float* qkv = ws + QKV_OFF;
  const float* Qg = qkv + (size_t)bh * 4096;
  const float4* Kg = (const float4*)(qkv + MATSZ + (size_t)bh * 4096);
  const float4* Vg = (const float4*)(qkv + 2 * (size_t)MATSZ + (size_t)bh * 4096);
  const int t = threadIdx.x;
  for (int k = t; k < 512; k += 256) {
    kslo[k] = Kg[2 * k]; kshi[k] = Kg[2 * k + 1];
    vslo[k] = Vg[2 * k]; vshi[k] = Vg[2 * k + 1];
  }
  __syncthreads();
  const int qslot = t >> 4, ko = t & 15;
  const int row0 = qt * 32 + qslot * 2;
  const float scale = 0.35355339059327373f;  // 1/sqrt(8)
  float4 qa0 = ((const float4*)(Qg + (size_t)row0 * 8))[0];
  float4 qb0 = ((const float4*)(Qg + (size_t)row0 * 8))[1];
  float4 qa1 = ((const float4*)(Qg + (size_t)(row0 + 1) * 8))[0];
  float4 qb1 = ((const float4*)(Qg + (size_t)(row0 + 1) * 8))[1];
  qa0.x *= scale; qa0.y *= scale; qa0.z *= scale; qa0.w *= scale;
  qb0.x *= scale; qb0.y *= scale; qb0.z *= scale; qb0.w *= scale;
  qa1.x *= scale; qa1.y *= scale; qa1.z *= scale; qa1.w *= scale;
  qb1.x *= scale; qb1.y *= scale; qb1.z *= scale; qb1.w *= scale;
  float l0 = 0.f, l1 = 0.f;
  float a0[8] = {0.f, 0.f, 0.f, 0.f, 0.f, 0.f, 0.f, 0.f};
  float a1[8] = {0.f, 0.f, 0.f, 0.f, 0.f, 0.f, 0.f, 0.f};
#pragma unroll 2
  for (int i = 0; i < 32; ++i) {
    int k = i * 16 + ko;  // 16 distinct rows/wave-instr -> 2-way = free
    float4 kx = kslo[k], ky = kshi[k];
    float s0 = qa0.x * kx.x + qa0.y * kx.y + qa0.z * kx.z + qa0.w * kx.w +
               qb0.x * ky.x + qb0.y * ky.y + qb0.z * ky.z + qb0.w * ky.w;
    float s1 = qa1.x * kx.x + qa1.y * kx.y + qa1.z * kx.z + qa1.w * kx.w +
               qb1.x * ky.x + qb1.y * ky.y + qb1.z * ky.z + qb1.w * ky.w;
    float p0 = __expf(s0), p1 = __expf(s1);  // |s| <= 2.83: no max needed
    float4 vx = vslo[k], vy = vshi[k];
    l0 += p0; l1 += p1;
    a0[0] = fmaf(p0, vx.x, a0[0]); a1[0] = fmaf(p1, vx.x, a1[0]);
    a0[1] = fmaf(p0, vx.y, a0[1]); a1[1] = fmaf(p1, vx.y, a1[1]);
    a0[2] = fmaf(p0, vx.z, a0[2]); a1[2] = fmaf(p1, vx.z, a1[2]);
    a0[3] = fmaf(p0, vx.w, a0[3]); a1[3] = fmaf(p1, vx.w, a1[3]);
    a0[4] = fmaf(p0, vy.x, a0[4]); a1[4] = fmaf(p1, vy.x, a1[4]);
    a0[5] = fmaf(p0, vy.y, a0[5]); a1[5] = fmaf(p1, vy.y, a1[5]);
    a0[6] = fmaf(p0, vy.z, a0[6]); a1[6] = fmaf(p1, vy.z, a1[6]);
    a0[7] = fmaf(p0, vy.w, a0[7]); a1[7] = fmaf(p1, vy.w, a1[7]);
  }
#pragma unroll
  for (int mm = 1; mm <= 8; mm <<= 1) {  // reduce over 16 k-octants
    l0 += __shfl_xor(l0, mm);
    l1 += __shfl_xor(l1, mm);
#pragma unroll
    for (int j = 0; j < 8; ++j) {
      a0[j] += __shfl_xor(a0[j], mm);
      a1[j] += __shfl_xor(a1[j], mm);
    }
  }
  if (ko == 0) {
    float i0 = 1.f / l0, i1 = 1.f / l1;
    int b = bh >> 4, h = bh & 15;
    float* aout = ws + AOUT_OFF;
    float* d0 = aout + ((size_t)(b * 512 + row0)) * 128 + h * 8;
    ((float4*)d0)[0] = make_float4(a0[0] * i0, a0[1] * i0, a0[2] * i0, a0[3] * i0);
    ((float4*)d0)[1] = make_float4(a0[4] * i0, a0[5] * i0, a0[6] * i0, a0[7] * i0);
    float* d1 = d0 + 128;
    ((float4*)d1)[0] = make_float4(a1[0] * i1, a1[1] * i1, a1[2] * i1, a1[3] * i1);
    ((float4*)d1)[1] = make_float4(a1[4] * i1, a1[5] * i1, a1[6] * i1, a1[7] * i1);
  }
}

// ---------------- k_out: out = aout @ Wo^T -----------------------------------
// grid 512 blocks of 4 rows; thread = 1 row x 2 cols, full K.
__global__ __launch_bounds__(256, 4) void k_out(
    const float* __restrict__ ws, float* __restrict__ out) {
  __shared__ float as_[4][128];
  const int t = threadIdx.x;
  const int tile = blockIdx.x;  // 0..511
  const float* aout = ws + AOUT_OFF;
  if (t < 128)
    ((float4*)&as_[0][0])[t] = ((const float4*)(aout + (size_t)tile * 512))[t];
  __syncthreads();
  const int cg = t & 63, rg = t >> 6;
  const float2* wt2 = (const float2*)(ws + WT_OFF + 3 * 16384);
  const float* ar = &as_[rg][0];
  float2 acc = make_float2(0.f, 0.f);
#pragma unroll 8
  for (int k = 0; k < 128; ++k) {
    float2 w = wt2[k * 64 + cg];  // coalesced
    float xv = ar[k];             // LDS broadcast
    acc.x = fmaf(xv, w.x, acc.x);
    acc.y = fmaf(xv, w.y, acc.y);
  }
  ((float2*)(out + (size_t)(tile * 4 + rg) * 128))[cg] = acc;
}

extern "C" void kernel_launch(void* const* d_in, const int* in_sizes, int n_in,
                              void* d_out, int out_size, void* d_ws, size_t ws_size,
                              hipStream_t stream) {
  const float* x  = (const float*)d_in[0];
  const float* Wq = (const float*)d_in[1];
  const float* Wk = (const float*)d_in[2];
  const float* Wv = (const float*)d_in[3];
  const float* Wo = (const float*)d_in[4];
  const float* qp = (const float*)d_in[5];
  float* out = (float*)d_out;
  float* ws = (float*)d_ws;

  hipLaunchKernelGGL(k_prep, dim3(16, 4), dim3(256), 0, stream,
                     Wq, Wk, Wv, Wo, ws);
  hipLaunchKernelGGL(k_qkvq, dim3(256, 3), dim3(256), 0, stream, x, qp, ws);
  hipLaunchKernelGGL(k_attn, dim3(16, 64), dim3(256), 0, stream, ws);
  hipLaunchKernelGGL(k_out, dim3(512), dim3(256), 0, stream, ws, out);
}

// Round 4
// 45.955 us; speedup vs baseline: 3.7696x; 1.0733x over previous
//
#include <hip/hip_runtime.h>
#include <cmath>

#define MATSZ 262144                  // 2048 * 128
#define WT_OFF 0                      // wt[4][128][128]: wt[m][k][c] = W_m[c][k]
#define QKV_OFF 65536                 // qkv[3][64][512][8]
#define AOUT_OFF (65536 + 3 * MATSZ)  // aout[2048][128]

// ---------------- k_prep: transpose the 4 weight matrices --------------------
__global__ __launch_bounds__(256) void k_prep(
    const float* __restrict__ Wq, const float* __restrict__ Wk,
    const float* __restrict__ Wv, const float* __restrict__ Wo,
    float* __restrict__ ws) {
  __shared__ float s[32][33];
  const int m = blockIdx.y;
  const int tr = blockIdx.x >> 2;  // c-tile
  const int tc = blockIdx.x & 3;   // k-tile
  const float* W = (m == 0) ? Wq : (m == 1) ? Wk : (m == 2) ? Wv : Wo;
  const int lk = threadIdx.x & 31;
  const int l0 = threadIdx.x >> 5;
#pragma unroll
  for (int i = 0; i < 4; ++i) {
    int lc = l0 + i * 8;
    s[lc][lk] = W[(size_t)(tr * 32 + lc) * 128 + tc * 32 + lk];  // coalesced
  }
  __syncthreads();
  float* wt = ws + WT_OFF + m * 16384;
#pragma unroll
  for (int i = 0; i < 4; ++i) {
    int lkk = l0 + i * 8;
    wt[(size_t)(tc * 32 + lkk) * 128 + tr * 32 + lk] = s[lk][lkk];  // coalesced
  }
}

// ---------------- k_qkvq: QKV projection + quantum, all-register tail --------
// grid (128,3): 16-row tile x matrix. thread = 2 rows x 4 cols (cols 4cg..4cg+3).
// Head h = cg>>1; even cg owns cols j=0..3 of h, odd cg owns j=4..7.
__global__ __launch_bounds__(256, 4) void k_qkvq(
    const float* __restrict__ x, const float* __restrict__ qp,
    float* __restrict__ ws) {
  __shared__ float xs[16][128];
  const int t = threadIdx.x;
  const int tile = blockIdx.x;  // 0..127
  const int m = blockIdx.y;     // 0..2
  {
    const float4* xg = (const float4*)(x + (size_t)tile * 2048);
    float4* xv = (float4*)&xs[0][0];
    xv[t] = xg[t];
    xv[t + 256] = xg[t + 256];
  }
  __syncthreads();
  const int cg = t & 31, rg = t >> 5;  // rg: 8 groups of 2 rows
  const float4* wt4 = (const float4*)(ws + WT_OFF + m * 16384);
  const float4* xs4 = (const float4*)&xs[0][0];
  float4 acc0 = make_float4(0.f, 0.f, 0.f, 0.f);
  float4 acc1 = make_float4(0.f, 0.f, 0.f, 0.f);
#pragma unroll 4
  for (int kc = 0; kc < 32; ++kc) {
    float4 w0 = wt4[(kc * 4 + 0) * 32 + cg];
    float4 w1 = wt4[(kc * 4 + 1) * 32 + cg];
    float4 w2 = wt4[(kc * 4 + 2) * 32 + cg];
    float4 w3 = wt4[(kc * 4 + 3) * 32 + cg];
    float4 xa = xs4[(rg * 2 + 0) * 32 + kc];  // LDS b128, 4 k's at once
    float4 xb = xs4[(rg * 2 + 1) * 32 + kc];
    acc0.x = fmaf(xa.x, w0.x, acc0.x); acc0.y = fmaf(xa.x, w0.y, acc0.y);
    acc0.z = fmaf(xa.x, w0.z, acc0.z); acc0.w = fmaf(xa.x, w0.w, acc0.w);
    acc0.x = fmaf(xa.y, w1.x, acc0.x); acc0.y = fmaf(xa.y, w1.y, acc0.y);
    acc0.z = fmaf(xa.y, w1.z, acc0.z); acc0.w = fmaf(xa.y, w1.w, acc0.w);
    acc0.x = fmaf(xa.z, w2.x, acc0.x); acc0.y = fmaf(xa.z, w2.y, acc0.y);
    acc0.z = fmaf(xa.z, w2.z, acc0.z); acc0.w = fmaf(xa.z, w2.w, acc0.w);
    acc0.x = fmaf(xa.w, w3.x, acc0.x); acc0.y = fmaf(xa.w, w3.y, acc0.y);
    acc0.z = fmaf(xa.w, w3.z, acc0.z); acc0.w = fmaf(xa.w, w3.w, acc0.w);
    acc1.x = fmaf(xb.x, w0.x, acc1.x); acc1.y = fmaf(xb.x, w0.y, acc1.y);
    acc1.z = fmaf(xb.x, w0.z, acc1.z); acc1.w = fmaf(xb.x, w0.w, acc1.w);
    acc1.x = fmaf(xb.y, w1.x, acc1.x); acc1.y = fmaf(xb.y, w1.y, acc1.y);
    acc1.z = fmaf(xb.y, w1.z, acc1.z); acc1.w = fmaf(xb.y, w1.w, acc1.w);
    acc1.x = fmaf(xb.z, w2.x, acc1.x); acc1.y = fmaf(xb.z, w2.y, acc1.y);
    acc1.z = fmaf(xb.z, w2.z, acc1.z); acc1.w = fmaf(xb.z, w2.w, acc1.w);
    acc1.x = fmaf(xb.w, w3.x, acc1.x); acc1.y = fmaf(xb.w, w3.y, acc1.y);
    acc1.z = fmaf(xb.w, w3.z, acc1.z); acc1.w = fmaf(xb.w, w3.w, acc1.w);
  }
  // quantum closed form: theta -> cos -> parity-chain prefix products.
  const int j0 = (cg & 1) * 4;
  float4 qs;
  qs.x = qp[j0 + 0] + qp[8 + j0 + 0];
  qs.y = qp[j0 + 1] + qp[8 + j0 + 1];
  qs.z = qp[j0 + 2] + qp[8 + j0 + 2];
  qs.w = qp[j0 + 3] + qp[8 + j0 + 3];
  const int h = cg >> 1;
  const bool hi = (cg & 1) != 0;
#pragma unroll
  for (int r = 0; r < 2; ++r) {
    float4 a = (r == 0) ? acc0 : acc1;
    float4 c;
    c.x = __cosf(a.x + qs.x);
    c.y = __cosf(a.y + qs.y);
    c.z = __cosf(a.z + qs.z);
    c.w = __cosf(a.w + qs.w);
    float4 u;  // local prefix: (c0, c1, c0c2, c1c3) -- same formula both halves
    u.x = c.x; u.y = c.y; u.z = c.x * c.z; u.w = c.y * c.w;
    float gz = __shfl_xor(u.z, 1);  // even lane's o2 -> odd lane
    float gw = __shfl_xor(u.w, 1);  // even lane's o3 -> odd lane
    float mz = hi ? gz : 1.f, mw = hi ? gw : 1.f;
    float4 o;
    o.x = u.x * mz; o.y = u.y * mw; o.z = u.z * mz; o.w = u.w * mw;
    int row = tile * 16 + rg * 2 + r;
    int b = row >> 9, s = row & 511;
    float* dst = ws + QKV_OFF + (size_t)m * MATSZ +
                 ((size_t)((b << 4) + h) * 512 + s) * 8 + (hi ? 4 : 0);
    *(float4*)dst = o;
  }
}

// ---------------- k_attn: attention per (bh, 64-row q-tile) ------------------
// grid (8,64); 256 thr = 16 qslots (4 rows) x 16 k-octants. K/V rows as lo/hi
// float4 arrays; per wave 16 distinct addrs x 4-way broadcast = conflict-free.
__global__ __launch_bounds__(256, 4) void k_attn(
    float* __restrict__ ws) {
  __shared__ float4 kslo[512], kshi[512], vslo[512], vshi[512];
  const int qt = blockIdx.x;  // 0..7
  const int bh = blockIdx.y;  // 0..63
  const float* qkv = ws + QKV_OFF;
  const float* Qg = qkv + (size_t)bh * 4096;
  const float4* Kg = (const float4*)(qkv + MATSZ + (size_t)bh * 4096);
  const float4* Vg = (const float4*)(qkv + 2 * (size_t)MATSZ + (size_t)bh * 4096);
  const int t = threadIdx.x;
  for (int k = t; k < 512; k += 256) {
    kslo[k] = Kg[2 * k]; kshi[k] = Kg[2 * k + 1];
    vslo[k] = Vg[2 * k]; vshi[k] = Vg[2 * k + 1];
  }
  __syncthreads();
  const int qslot = t >> 4, ko = t & 15;
  const int row0 = qt * 64 + qslot * 4;
  const float scale = 0.35355339059327373f;  // 1/sqrt(8)
  float4 qa[4], qb[4];
#pragma unroll
  for (int r = 0; r < 4; ++r) {
    qa[r] = ((const float4*)(Qg + (size_t)(row0 + r) * 8))[0];
    qb[r] = ((const float4*)(Qg + (size_t)(row0 + r) * 8))[1];
    qa[r].x *= scale; qa[r].y *= scale; qa[r].z *= scale; qa[r].w *= scale;
    qb[r].x *= scale; qb[r].y *= scale; qb[r].z *= scale; qb[r].w *= scale;
  }
  float l[4] = {0.f, 0.f, 0.f, 0.f};
  float a[4][8];
#pragma unroll
  for (int r = 0; r < 4; ++r)
#pragma unroll
    for (int j = 0; j < 8; ++j) a[r][j] = 0.f;
#pragma unroll 2
  for (int i = 0; i < 32; ++i) {
    int k = i * 16 + ko;
    float4 kx = kslo[k], ky = kshi[k];
    float4 vx = vslo[k], vy = vshi[k];
#pragma unroll
    for (int r = 0; r < 4; ++r) {
      float s = qa[r].x * kx.x + qa[r].y * kx.y + qa[r].z * kx.z + qa[r].w * kx.w +
                qb[r].x * ky.x + qb[r].y * ky.y + qb[r].z * ky.z + qb[r].w * ky.w;
      float p = __expf(s);  // |s| <= 2.83: no max subtraction needed
      l[r] += p;
      a[r][0] = fmaf(p, vx.x, a[r][0]);
      a[r][1] = fmaf(p, vx.y, a[r][1]);
      a[r][2] = fmaf(p, vx.z, a[r][2]);
      a[r][3] = fmaf(p, vx.w, a[r][3]);
      a[r][4] = fmaf(p, vy.x, a[r][4]);
      a[r][5] = fmaf(p, vy.y, a[r][5]);
      a[r][6] = fmaf(p, vy.z, a[r][6]);
      a[r][7] = fmaf(p, vy.w, a[r][7]);
    }
  }
#pragma unroll
  for (int mm = 1; mm <= 8; mm <<= 1) {  // reduce over 16 k-octants
#pragma unroll
    for (int r = 0; r < 4; ++r) {
      l[r] += __shfl_xor(l[r], mm);
#pragma unroll
      for (int j = 0; j < 8; ++j) a[r][j] += __shfl_xor(a[r][j], mm);
    }
  }
  if (ko == 0) {
    int b = bh >> 4, h = bh & 15;
    float* aout = ws + AOUT_OFF;
#pragma unroll
    for (int r = 0; r < 4; ++r) {
      float inv = 1.f / l[r];
      float* d = aout + ((size_t)(b * 512 + row0 + r)) * 128 + h * 8;
      ((float4*)d)[0] = make_float4(a[r][0] * inv, a[r][1] * inv,
                                    a[r][2] * inv, a[r][3] * inv);
      ((float4*)d)[1] = make_float4(a[r][4] * inv, a[r][5] * inv,
                                    a[r][6] * inv, a[r][7] * inv);
    }
  }
}

// ---------------- k_out: out = aout @ Wo^T -----------------------------------
// grid 128 blocks (16-row tiles); thread = 2 rows x 4 cols, full K.
__global__ __launch_bounds__(256, 4) void k_out(
    const float* __restrict__ ws, float* __restrict__ out) {
  __shared__ float as_[16][128];
  const int t = threadIdx.x;
  const int tile = blockIdx.x;  // 0..127
  const float* aout = ws + AOUT_OFF;
  {
    const float4* ag = (const float4*)(aout + (size_t)tile * 2048);
    float4* av = (float4*)&as_[0][0];
    av[t] = ag[t];
    av[t + 256] = ag[t + 256];
  }
  __syncthreads();
  const int cg = t & 31, rg = t >> 5;
  const float4* wt4 = (const float4*)(ws + WT_OFF + 3 * 16384);
  const float4* as4 = (const float4*)&as_[0][0];
  float4 acc0 = make_float4(0.f, 0.f, 0.f, 0.f);
  float4 acc1 = make_float4(0.f, 0.f, 0.f, 0.f);
#pragma unroll 4
  for (int kc = 0; kc < 32; ++kc) {
    float4 w0 = wt4[(kc * 4 + 0) * 32 + cg];
    float4 w1 = wt4[(kc * 4 + 1) * 32 + cg];
    float4 w2 = wt4[(kc * 4 + 2) * 32 + cg];
    float4 w3 = wt4[(kc * 4 + 3) * 32 + cg];
    float4 xa = as4[(rg * 2 + 0) * 32 + kc];
    float4 xb = as4[(rg * 2 + 1) * 32 + kc];
    acc0.x = fmaf(xa.x, w0.x, acc0.x); acc0.y = fmaf(xa.x, w0.y, acc0.y);
    acc0.z = fmaf(xa.x, w0.z, acc0.z); acc0.w = fmaf(xa.x, w0.w, acc0.w);
    acc0.x = fmaf(xa.y, w1.x, acc0.x); acc0.y = fmaf(xa.y, w1.y, acc0.y);
    acc0.z = fmaf(xa.y, w1.z, acc0.z); acc0.w = fmaf(xa.y, w1.w, acc0.w);
    acc0.x = fmaf(xa.z, w2.x, acc0.x); acc0.y = fmaf(xa.z, w2.y, acc0.y);
    acc0.z = fmaf(xa.z, w2.z, acc0.z); acc0.w = fmaf(xa.z, w2.w, acc0.w);
    acc0.x = fmaf(xa.w, w3.x, acc0.x); acc0.y = fmaf(xa.w, w3.y, acc0.y);
    acc0.z = fmaf(xa.w, w3.z, acc0.z); acc0.w = fmaf(xa.w, w3.w, acc0.w);
    acc1.x = fmaf(xb.x, w0.x, acc1.x); acc1.y = fmaf(xb.x, w0.y, acc1.y);
    acc1.z = fmaf(xb.x, w0.z, acc1.z); acc1.w = fmaf(xb.x, w0.w, acc1.w);
    acc1.x = fmaf(xb.y, w1.x, acc1.x); acc1.y = fmaf(xb.y, w1.y, acc1.y);
    acc1.z = fmaf(xb.y, w1.z, acc1.z); acc1.w = fmaf(xb.y, w1.w, acc1.w);
    acc1.x = fmaf(xb.z, w2.x, acc1.x); acc1.y = fmaf(xb.z, w2.y, acc1.y);
    acc1.z = fmaf(xb.z, w2.z, acc1.z); acc1.w = fmaf(xb.z, w2.w, acc1.w);
    acc1.x = fmaf(xb.w, w3.x, acc1.x); acc1.y = fmaf(xb.w, w3.y, acc1.y);
    acc1.z = fmaf(xb.w, w3.z, acc1.z); acc1.w = fmaf(xb.w, w3.w, acc1.w);
  }
  const int row = tile * 16 + rg * 2;
  ((float4*)(out + (size_t)row * 128))[cg] = acc0;
  ((float4*)(out + (size_t)(row + 1) * 128))[cg] = acc1;
}

extern "C" void kernel_launch(void* const* d_in, const int* in_sizes, int n_in,
                              void* d_out, int out_size, void* d_ws, size_t ws_size,
                              hipStream_t stream) {
  const float* x  = (const float*)d_in[0];
  const float* Wq = (const float*)d_in[1];
  const float* Wk = (const float*)d_in[2];
  const float* Wv = (const float*)d_in[3];
  const float* Wo = (const float*)d_in[4];
  const float* qp = (const float*)d_in[5];
  float* out = (float*)d_out;
  float* ws = (float*)d_ws;

  hipLaunchKernelGGL(k_prep, dim3(16, 4), dim3(256), 0, stream,
                     Wq, Wk, Wv, Wo, ws);
  hipLaunchKernelGGL(k_qkvq, dim3(128, 3), dim3(256), 0, stream, x, qp, ws);
  hipLaunchKernelGGL(k_attn, dim3(8, 64), dim3(256), 0, stream, ws);
  hipLaunchKernelGGL(k_out, dim3(128), dim3(256), 0, stream, ws, out);
}

// Round 5
// 41.609 us; speedup vs baseline: 4.1633x; 1.1044x over previous
//
#include <hip/hip_runtime.h>
#include <cmath>

#define MATSZ 262144                  // 2048 * 128
#define QKV_OFF 65536                 // qkv[3][64][512][8]
#define AOUT_OFF (65536 + 3 * MATSZ)  // aout[2048][128]

// ---------------- k_qkvq: QKV projection + quantum closed form ---------------
// No weight transpose: thread = (col e, K-half). W row fragment (16 float4) in
// registers, x rows broadcast from LDS, K-halves combined via LDS partials.
// grid (256,3): 8-row tile x matrix -> 768 blocks = 3/CU.
__global__ __launch_bounds__(256, 3) void k_qkvq(
    const float* __restrict__ x, const float* __restrict__ Wq,
    const float* __restrict__ Wk, const float* __restrict__ Wv,
    const float* __restrict__ qp, float* __restrict__ ws) {
  __shared__ float xs[8][128];     // 4 KB
  __shared__ float th[2][8][128];  // 8 KB partial sums per K-half
  const int t = threadIdx.x;
  const int tile = blockIdx.x;  // 0..255 (8 rows each)
  const int m = blockIdx.y;     // 0..2
  const float* W = (m == 0) ? Wq : (m == 1) ? Wk : Wv;
  {  // stage x tile: 8*32 = 256 float4, one per thread
    ((float4*)&xs[0][0])[t] = ((const float4*)(x + (size_t)tile * 1024))[t];
  }
  const int e = t & 127, half = t >> 7;
  float4 w[16];
  {
    const float4* wr = (const float4*)W + (size_t)e * 32 + half * 16;
#pragma unroll
    for (int i = 0; i < 16; ++i) w[i] = wr[i];  // row fragment, 64 VGPR
  }
  __syncthreads();
  const float4* xs4 = (const float4*)&xs[0][0];
#pragma unroll
  for (int r = 0; r < 8; ++r) {
    float a = 0.f;
    const float4* xr = xs4 + r * 32 + half * 16;
#pragma unroll
    for (int i = 0; i < 16; ++i) {
      float4 xv = xr[i];  // LDS broadcast (wave-uniform addr)
      a = fmaf(xv.x, w[i].x, a);
      a = fmaf(xv.y, w[i].y, a);
      a = fmaf(xv.z, w[i].z, a);
      a = fmaf(xv.w, w[i].w, a);
    }
    th[half][r][e] = a;  // lanes e-consecutive: conflict-free
  }
  __syncthreads();
  // quantum tail: thread = (row rg, half-head cg); cols 4cg..4cg+3.
  const int cg = t & 31, rg = t >> 5;
  const float4* th4 = (const float4*)&th[0][0][0];
  float4 s0 = th4[rg * 32 + cg];
  float4 s1 = th4[256 + rg * 32 + cg];
  float4 a4 = make_float4(s0.x + s1.x, s0.y + s1.y, s0.z + s1.z, s0.w + s1.w);
  const int j0 = (cg & 1) * 4;
  float4 qs;
  qs.x = qp[j0 + 0] + qp[8 + j0 + 0];
  qs.y = qp[j0 + 1] + qp[8 + j0 + 1];
  qs.z = qp[j0 + 2] + qp[8 + j0 + 2];
  qs.w = qp[j0 + 3] + qp[8 + j0 + 3];
  float4 c;
  c.x = __cosf(a4.x + qs.x);
  c.y = __cosf(a4.y + qs.y);
  c.z = __cosf(a4.z + qs.z);
  c.w = __cosf(a4.w + qs.w);
  float4 u;  // local prefix: (c0, c1, c0c2, c1c3) in this half's numbering
  u.x = c.x; u.y = c.y; u.z = c.x * c.z; u.w = c.y * c.w;
  float gz = __shfl_xor(u.z, 1);  // even lane's (c0*c2) -> odd lane
  float gw = __shfl_xor(u.w, 1);  // even lane's (c1*c3) -> odd lane
  const bool hi = (cg & 1) != 0;
  float mz = hi ? gz : 1.f, mw = hi ? gw : 1.f;
  float4 o;
  o.x = u.x * mz; o.y = u.y * mw; o.z = u.z * mz; o.w = u.w * mw;
  const int h = cg >> 1;
  int row = tile * 8 + rg;
  int b = row >> 9, s = row & 511;
  float* dst = ws + QKV_OFF + (size_t)m * MATSZ +
               ((size_t)((b << 4) + h) * 512 + s) * 8 + (hi ? 4 : 0);
  *(float4*)dst = o;
}

// ---------------- k_attn: attention per (bh, 64-row q-tile) ------------------
// grid (8,64); 256 thr = 16 qslots (4 rows) x 16 k-octants. K/V rows as lo/hi
// float4 arrays; per wave 16 distinct addrs x 4-way broadcast = conflict-free.
__global__ __launch_bounds__(256, 4) void k_attn(
    float* __restrict__ ws) {
  __shared__ float4 kslo[512], kshi[512], vslo[512], vshi[512];
  const int qt = blockIdx.x;  // 0..7
  const int bh = blockIdx.y;  // 0..63
  const float* qkv = ws + QKV_OFF;
  const float* Qg = qkv + (size_t)bh * 4096;
  const float4* Kg = (const float4*)(qkv + MATSZ + (size_t)bh * 4096);
  const float4* Vg = (const float4*)(qkv + 2 * (size_t)MATSZ + (size_t)bh * 4096);
  const int t = threadIdx.x;
  for (int k = t; k < 512; k += 256) {
    kslo[k] = Kg[2 * k]; kshi[k] = Kg[2 * k + 1];
    vslo[k] = Vg[2 * k]; vshi[k] = Vg[2 * k + 1];
  }
  __syncthreads();
  const int qslot = t >> 4, ko = t & 15;
  const int row0 = qt * 64 + qslot * 4;
  const float scale = 0.35355339059327373f;  // 1/sqrt(8)
  float4 qa[4], qb[4];
#pragma unroll
  for (int r = 0; r < 4; ++r) {
    qa[r] = ((const float4*)(Qg + (size_t)(row0 + r) * 8))[0];
    qb[r] = ((const float4*)(Qg + (size_t)(row0 + r) * 8))[1];
    qa[r].x *= scale; qa[r].y *= scale; qa[r].z *= scale; qa[r].w *= scale;
    qb[r].x *= scale; qb[r].y *= scale; qb[r].z *= scale; qb[r].w *= scale;
  }
  float l[4] = {0.f, 0.f, 0.f, 0.f};
  float a[4][8];
#pragma unroll
  for (int r = 0; r < 4; ++r)
#pragma unroll
    for (int j = 0; j < 8; ++j) a[r][j] = 0.f;
#pragma unroll 2
  for (int i = 0; i < 32; ++i) {
    int k = i * 16 + ko;
    float4 kx = kslo[k], ky = kshi[k];
    float4 vx = vslo[k], vy = vshi[k];
#pragma unroll
    for (int r = 0; r < 4; ++r) {
      float s = qa[r].x * kx.x + qa[r].y * kx.y + qa[r].z * kx.z + qa[r].w * kx.w +
                qb[r].x * ky.x + qb[r].y * ky.y + qb[r].z * ky.z + qb[r].w * ky.w;
      float p = __expf(s);  // |s| <= 2.83: no max subtraction needed
      l[r] += p;
      a[r][0] = fmaf(p, vx.x, a[r][0]);
      a[r][1] = fmaf(p, vx.y, a[r][1]);
      a[r][2] = fmaf(p, vx.z, a[r][2]);
      a[r][3] = fmaf(p, vx.w, a[r][3]);
      a[r][4] = fmaf(p, vy.x, a[r][4]);
      a[r][5] = fmaf(p, vy.y, a[r][5]);
      a[r][6] = fmaf(p, vy.z, a[r][6]);
      a[r][7] = fmaf(p, vy.w, a[r][7]);
    }
  }
#pragma unroll
  for (int mm = 1; mm <= 8; mm <<= 1) {  // reduce over 16 k-octants
#pragma unroll
    for (int r = 0; r < 4; ++r) {
      l[r] += __shfl_xor(l[r], mm);
#pragma unroll
      for (int j = 0; j < 8; ++j) a[r][j] += __shfl_xor(a[r][j], mm);
    }
  }
  if (ko == 0) {
    int b = bh >> 4, h = bh & 15;
    float* aout = ws + AOUT_OFF;
#pragma unroll
    for (int r = 0; r < 4; ++r) {
      float inv = 1.f / l[r];
      float* d = aout + ((size_t)(b * 512 + row0 + r)) * 128 + h * 8;
      ((float4*)d)[0] = make_float4(a[r][0] * inv, a[r][1] * inv,
                                    a[r][2] * inv, a[r][3] * inv);
      ((float4*)d)[1] = make_float4(a[r][4] * inv, a[r][5] * inv,
                                    a[r][6] * inv, a[r][7] * inv);
    }
  }
}

// ---------------- k_out: out = aout @ Wo^T -----------------------------------
// Same w-in-registers structure as k_qkvq, no transpose. grid 256 (8-row tiles).
__global__ __launch_bounds__(256, 3) void k_out(
    const float* __restrict__ ws, const float* __restrict__ Wo,
    float* __restrict__ out) {
  __shared__ float as_[8][128];    // 4 KB
  __shared__ float th[2][8][128];  // 8 KB
  const int t = threadIdx.x;
  const int tile = blockIdx.x;  // 0..255
  const float* aout = ws + AOUT_OFF;
  {
    ((float4*)&as_[0][0])[t] = ((const float4*)(aout + (size_t)tile * 1024))[t];
  }
  const int e = t & 127, half = t >> 7;
  float4 w[16];
  {
    const float4* wr = (const float4*)Wo + (size_t)e * 32 + half * 16;
#pragma unroll
    for (int i = 0; i < 16; ++i) w[i] = wr[i];
  }
  __syncthreads();
  const float4* as4 = (const float4*)&as_[0][0];
#pragma unroll
  for (int r = 0; r < 8; ++r) {
    float a = 0.f;
    const float4* ar = as4 + r * 32 + half * 16;
#pragma unroll
    for (int i = 0; i < 16; ++i) {
      float4 av = ar[i];  // LDS broadcast
      a = fmaf(av.x, w[i].x, a);
      a = fmaf(av.y, w[i].y, a);
      a = fmaf(av.z, w[i].z, a);
      a = fmaf(av.w, w[i].w, a);
    }
    th[half][r][e] = a;
  }
  __syncthreads();
  const int cg = t & 31, rg = t >> 5;
  const float4* th4 = (const float4*)&th[0][0][0];
  float4 s0 = th4[rg * 32 + cg];
  float4 s1 = th4[256 + rg * 32 + cg];
  float4 o = make_float4(s0.x + s1.x, s0.y + s1.y, s0.z + s1.z, s0.w + s1.w);
  ((float4*)(out + (size_t)(tile * 8 + rg) * 128))[cg] = o;
}

extern "C" void kernel_launch(void* const* d_in, const int* in_sizes, int n_in,
                              void* d_out, int out_size, void* d_ws, size_t ws_size,
                              hipStream_t stream) {
  const float* x  = (const float*)d_in[0];
  const float* Wq = (const float*)d_in[1];
  const float* Wk = (const float*)d_in[2];
  const float* Wv = (const float*)d_in[3];
  const float* Wo = (const float*)d_in[4];
  const float* qp = (const float*)d_in[5];
  float* out = (float*)d_out;
  float* ws = (float*)d_ws;

  hipLaunchKernelGGL(k_qkvq, dim3(256, 3), dim3(256), 0, stream,
                     x, Wq, Wk, Wv, qp, ws);
  hipLaunchKernelGGL(k_attn, dim3(8, 64), dim3(256), 0, stream, ws);
  hipLaunchKernelGGL(k_out, dim3(256), dim3(256), 0, stream, ws, Wo, out);
}